// Round 4
// baseline (741.043 us; speedup 1.0000x reference)
//
#include <hip/hip_runtime.h>
#include <hip/hip_bf16.h>

#define BB 8
#define LL 1024
#define TT 10
#define TILE 64
#define NTILE (LL/TILE)            // 16
#define NPAIR (NTILE*(NTILE+1)/2)  // 136
#define SPAD 65                    // 64 + 1 pad, conflict-free transpose reads
#define S_CONST 2.1972245773362196f

static __device__ __forceinline__ float sigm(float v) {
    return 1.0f / (1.0f + __expf(-v));
}

static __device__ __forceinline__ void pair_from_idx(int p, int& I, int& J) {
    int i = 0;
    while (p >= NTILE - i) { p -= NTILE - i; i++; }
    I = i; J = i + p;
}

// m[i,j] = ba_i*bu_j + ba_j*bu_i + bc_i*bg_j + bc_j*bg_i + bu_i*bg_j + bu_j*bg_i
static __device__ __forceinline__ float compute_m(const float* xI, const float* xJ, int r, int c) {
    float bai = xI[0*TILE + r], bui = xI[1*TILE + r], bci = xI[2*TILE + r], bgi = xI[3*TILE + r];
    float baj = xJ[0*TILE + c], buj = xJ[1*TILE + c], bcj = xJ[2*TILE + c], bgj = xJ[3*TILE + c];
    return bai*buj + baj*bui + bci*bgj + bcj*bgi + bui*bgj + buj*bgi;
}

// h = relu(W1 f + b1); out = relu(W2 h + b2).  w: [0..8]=W1 row-major [o][i], [9..11]=b1, [12..14]=W2, [15]=b2
static __device__ __forceinline__ float mlp3(float f0, float f1, float f2, const float* w) {
    float h0 = fmaxf(w[0]*f0 + w[1]*f1 + w[2]*f2 + w[9],  0.0f);
    float h1 = fmaxf(w[3]*f0 + w[4]*f1 + w[5]*f2 + w[10], 0.0f);
    float h2 = fmaxf(w[6]*f0 + w[7]*f1 + w[8]*f2 + w[11], 0.0f);
    return fmaxf(w[12]*h0 + w[13]*h1 + w[14]*h2 + w[15], 0.0f);
}

static __device__ __forceinline__ float ahnew_calc(float ah, float grad, float uuv, const float* w) {
    float va = mlp3(ah, grad, uuv, w);       // a-MLP  (w[0..15])
    float vr = mlp3(ah, grad, uuv, w + 16);  // rho-MLP (w[16..31])
    float v = fmaxf(fabsf(va) - vr, 0.0f);   // relu(|a| - rho); >=0 so clip(-1,1) == min(.,1)
    return fminf(v, 1.0f);
}

// uu = soft_sign(u - S)*u ; a_hat0 = sigmoid(uu)*soft_sign(uu - S)
__global__ void k_prep(const float* __restrict__ u,
                       float* __restrict__ uu, float* __restrict__ ahat) {
    const long long N = (long long)BB * LL * LL;
    for (long long i = (long long)blockIdx.x * blockDim.x + threadIdx.x; i < N;
         i += (long long)gridDim.x * blockDim.x) {
        float uv  = u[i];
        float uuv = sigm(2.0f * (uv - S_CONST)) * uv;
        float ah  = sigm(uuv) * sigm(2.0f * (uuv - S_CONST));
        uu[i]   = uuv;
        ahat[i] = ah;
    }
}

// rowsums of a0 = 0.5*(ah_ij^2 + ah_ji^2)*m  (tile-pair; a0 not materialized)
__global__ __launch_bounds__(256) void k_rs0(const float* __restrict__ ahat,
                                             const float* __restrict__ x,
                                             float* __restrict__ rs) {
    __shared__ float stB[TILE * SPAD];
    __shared__ float xI[4 * TILE], xJ[4 * TILE];
    __shared__ float rsI[TILE], rsJ[TILE];

    int b = blockIdx.x / NPAIR, p = blockIdx.x % NPAIR;
    int I, J; pair_from_idx(p, I, J);
    int Ib = I * TILE, Jb = J * TILE;
    bool diag = (I == J);
    int tid = threadIdx.x, c = tid & 63, rg = tid >> 6;

    { int row = tid >> 2, k = tid & 3;
      xI[k*TILE + row] = x[((size_t)b*LL + Ib + row)*4 + k];
      xJ[k*TILE + row] = x[((size_t)b*LL + Jb + row)*4 + k]; }
    if (tid < TILE) { rsI[tid] = 0.0f; rsJ[tid] = 0.0f; }

    size_t baseJI = ((size_t)b*LL + Jb)*LL + Ib;
    for (int k = 0; k < 16; k++) {
        int xr = rg + 4*k;
        stB[xr*SPAD + c] = ahat[baseJI + (size_t)xr*LL + c];
    }
    __syncthreads();

    size_t baseIJ = ((size_t)b*LL + Ib)*LL + Jb;
    float rsJ_th = 0.0f;
    for (int k = 0; k < 16; k++) {
        int r = rg + 4*k;
        float ah_ij = ahat[baseIJ + (size_t)r*LL + c];
        float ah_ji = stB[c*SPAD + r];
        float m = compute_m(xI, xJ, r, c);
        float a_val = 0.5f * (ah_ij*ah_ij + ah_ji*ah_ji) * m;
        float s = a_val;
        for (int off = 32; off; off >>= 1) s += __shfl_down(s, off, 64);
        if (c == 0) rsI[r] += s;
        if (!diag) rsJ_th += a_val;
    }
    if (!diag) atomicAdd(&rsJ[c], rsJ_th);
    __syncthreads();
    if (tid < TILE) atomicAdd(&rs[b*LL + Ib + tid], rsI[tid]);
    else if (!diag && tid < 2*TILE) atomicAdd(&rs[b*LL + Jb + (tid - TILE)], rsJ[tid - TILE]);
}

__global__ void k_rows_init(const float* __restrict__ rs0, float* __restrict__ lmbd,
                            float* __restrict__ ls, float* __restrict__ rs_other) {
    int i = blockIdx.x * blockDim.x + threadIdx.x;
    if (i < BB*LL) {
        float rsv = rs0[i];
        float l = fmaxf(rsv - 1.0f, 0.0f);   // W_PEN = 1
        lmbd[i] = l;
        ls[i] = l * sigm(2.0f * (rsv - 1.0f));
        rs_other[i] = 0.0f;
    }
}

__global__ __launch_bounds__(256) void k_step(
        const float* __restrict__ uu, float* ahat,
        const float* __restrict__ x,
        const float* __restrict__ ls, float* __restrict__ rs_next,
        const float* __restrict__ aW1, const float* __restrict__ ab1,
        const float* __restrict__ aW2, const float* __restrict__ ab2,
        const float* __restrict__ rW1, const float* __restrict__ rb1,
        const float* __restrict__ rW2, const float* __restrict__ rb2,
        float* __restrict__ out, int t) {
    __shared__ float stA[TILE * SPAD];   // uu_JI, then reused as a_val staging for JI tile
    __shared__ float stB[TILE * SPAD];   // ahat_JI, then reused as ah_new staging for JI tile
    __shared__ float xI[4 * TILE], xJ[4 * TILE];
    __shared__ float lsI[TILE], lsJ[TILE];
    __shared__ float w[32];
    __shared__ float rsI[TILE], rsJ[TILE];

    int b = blockIdx.x / NPAIR, p = blockIdx.x % NPAIR;
    int I, J; pair_from_idx(p, I, J);
    int Ib = I * TILE, Jb = J * TILE;
    bool diag = (I == J);
    int tid = threadIdx.x, c = tid & 63, rg = tid >> 6;

    if (tid < 32) {
        float v;
        if      (tid <  9) v = aW1[t*9 + tid];
        else if (tid < 12) v = ab1[t*3 + (tid-9)];
        else if (tid < 15) v = aW2[t*3 + (tid-12)];
        else if (tid < 16) v = ab2[t];
        else if (tid < 25) v = rW1[t*9 + (tid-16)];
        else if (tid < 28) v = rb1[t*3 + (tid-25)];
        else if (tid < 31) v = rW2[t*3 + (tid-28)];
        else               v = rb2[t];
        w[tid] = v;
    }
    { int row = tid >> 2, k = tid & 3;
      xI[k*TILE + row] = x[((size_t)b*LL + Ib + row)*4 + k];
      xJ[k*TILE + row] = x[((size_t)b*LL + Jb + row)*4 + k]; }
    if (tid < TILE) {
        lsI[tid] = ls[b*LL + Ib + tid];
        lsJ[tid] = ls[b*LL + Jb + tid];
        rsI[tid] = 0.0f; rsJ[tid] = 0.0f;
    }
    size_t baseJI = ((size_t)b*LL + Jb)*LL + Ib;
    for (int k = 0; k < 16; k++) {
        int xr = rg + 4*k;
        stA[xr*SPAD + c] = uu[baseJI + (size_t)xr*LL + c];
        stB[xr*SPAD + c] = ahat[baseJI + (size_t)xr*LL + c];
    }
    __syncthreads();

    size_t baseIJ = ((size_t)b*LL + Ib)*LL + Jb;
    size_t outBase = (((size_t)t*BB + b) * LL) * LL;
    float rsJ_th = 0.0f;
    for (int k = 0; k < 16; k++) {
        int r = rg + 4*k;
        size_t idxIJ = baseIJ + (size_t)r*LL + c;
        float uu_ij = uu[idxIJ];
        float ah_ij = ahat[idxIJ];
        float uu_ji = stA[c*SPAD + r];   // read before slot reuse (same thread owns slot)
        float ah_ji = stB[c*SPAD + r];
        float m = compute_m(xI, xJ, r, c);
        float gsum = -0.5f * (uu_ij + uu_ji) + lsI[r] + lsJ[c];
        float an_ij = ahnew_calc(ah_ij, ah_ij * m * gsum, uu_ij, w);
        float an_ji = ahnew_calc(ah_ji, ah_ji * m * gsum, uu_ji, w);  // diag: duplicate but correct
        float a_val = 0.5f * (an_ij*an_ij + an_ji*an_ji) * m;

        ahat[idxIJ] = an_ij;                                         // in-place: tile owned by block
        out[outBase + (size_t)(Ib + r)*LL + (Jb + c)] = a_val;

        float s = a_val;
        for (int off = 32; off; off >>= 1) s += __shfl_down(s, off, 64);
        if (c == 0) rsI[r] += s;                                     // wave-unique r, no race

        if (!diag) {
            stA[c*SPAD + r] = a_val;   // stage JI-tile output for coalesced writeback
            stB[c*SPAD + r] = an_ji;
            rsJ_th += a_val;           // a[Jb+c][Ib+r] == a_val (a symmetric)
        }
    }
    if (!diag) atomicAdd(&rsJ[c], rsJ_th);
    __syncthreads();
    if (!diag) {
        for (int k = 0; k < 16; k++) {
            int xr = rg + 4*k;
            ahat[baseJI + (size_t)xr*LL + c] = stB[xr*SPAD + c];
            out[outBase + (size_t)(Jb + xr)*LL + (Ib + c)] = stA[xr*SPAD + c];
        }
    }
    if (tid < TILE) atomicAdd(&rs_next[b*LL + Ib + tid], rsI[tid]);
    else if (!diag && tid < 2*TILE) atomicAdd(&rs_next[b*LL + Jb + (tid - TILE)], rsJ[tid - TILE]);
}

__global__ void k_rows_step(const float* __restrict__ rs_new, float* lmbd, float* __restrict__ ls,
                            float* __restrict__ rs_zero,
                            const float* __restrict__ lW1, const float* __restrict__ lb1,
                            const float* __restrict__ lW2, const float* __restrict__ lb2,
                            int t) {
    int i = blockIdx.x * blockDim.x + threadIdx.x;
    if (i < BB*LL) {
        float rsv = rs_new[i];
        float lg = fmaxf(rsv - 1.0f, 0.0f);
        float l0 = lmbd[i];
        float w0 = lW1[t*6 + 0], w1 = lW1[t*6 + 1];
        float w2 = lW1[t*6 + 2], w3 = lW1[t*6 + 3];
        float w4 = lW1[t*6 + 4], w5 = lW1[t*6 + 5];
        float b0 = lb1[t*3 + 0], b1 = lb1[t*3 + 1];
        float b2 = lb1[t*3 + 2];
        float v0 = lW2[t*3 + 0], v1 = lW2[t*3 + 1];
        float v2 = lW2[t*3 + 2];
        float c2 = lb2[t];
        float h0 = fmaxf(w0*l0 + w1*lg + b0, 0.0f);
        float h1 = fmaxf(w2*l0 + w3*lg + b1, 0.0f);
        float h2 = fmaxf(w4*l0 + w5*lg + b2, 0.0f);
        float ln = fmaxf(v0*h0 + v1*h1 + v2*h2 + c2, 0.0f);
        lmbd[i] = ln;
        ls[i] = ln * sigm(2.0f * (rsv - 1.0f));
        rs_zero[i] = 0.0f;   // prepare next accumulator
    }
}

extern "C" void kernel_launch(void* const* d_in, const int* in_sizes, int n_in,
                              void* d_out, int out_size, void* d_ws, size_t ws_size,
                              hipStream_t stream) {
    const float* u   = (const float*)d_in[0];
    const float* x   = (const float*)d_in[1];
    const float* aW1 = (const float*)d_in[3];
    const float* ab1 = (const float*)d_in[4];
    const float* aW2 = (const float*)d_in[5];
    const float* ab2 = (const float*)d_in[6];
    const float* rW1 = (const float*)d_in[7];
    const float* rb1 = (const float*)d_in[8];
    const float* rW2 = (const float*)d_in[9];
    const float* rb2 = (const float*)d_in[10];
    const float* lW1 = (const float*)d_in[11];
    const float* lb1 = (const float*)d_in[12];
    const float* lW2 = (const float*)d_in[13];
    const float* lb2 = (const float*)d_in[14];
    float* out = (float*)d_out;

    char* ws = (char*)d_ws;
    size_t matBytes = (size_t)BB * LL * LL * sizeof(float);
    float* uu   = (float*)ws;
    float* ahat = (float*)(ws + matBytes);
    float* rs0  = (float*)(ws + 2 * matBytes);
    float* rs1  = rs0 + BB*LL;
    float* lmbd = rs1 + BB*LL;
    float* ls   = lmbd + BB*LL;

    hipMemsetAsync(rs0, 0, BB*LL*sizeof(float), stream);
    hipLaunchKernelGGL(k_prep, dim3(2048), dim3(256), 0, stream, u, uu, ahat);
    hipLaunchKernelGGL(k_rs0, dim3(BB*NPAIR), dim3(256), 0, stream, ahat, x, rs0);
    hipLaunchKernelGGL(k_rows_init, dim3((BB*LL)/256), dim3(256), 0, stream, rs0, lmbd, ls, rs1);

    float* rsb[2] = {rs0, rs1};
    for (int t = 0; t < TT; ++t) {
        hipLaunchKernelGGL(k_step, dim3(BB*NPAIR), dim3(256), 0, stream,
                           uu, ahat, x, ls, rsb[(t+1)&1],
                           aW1, ab1, aW2, ab2, rW1, rb1, rW2, rb2, out, t);
        hipLaunchKernelGGL(k_rows_step, dim3((BB*LL)/256), dim3(256), 0, stream,
                           rsb[(t+1)&1], lmbd, ls, rsb[t&1], lW1, lb1, lW2, lb2, t);
    }
}

// Round 5
// 708.705 us; speedup vs baseline: 1.0456x; 1.0456x over previous
//
#include <hip/hip_runtime.h>
#include <hip/hip_bf16.h>

#define BB 8
#define LL 1024
#define TT 10
#define TILE 64
#define NTILE (LL/TILE)            // 16
#define NPAIR (NTILE*(NTILE+1)/2)  // 136
#define SPAD 65                    // 64 + 1 pad, conflict-free transpose reads
#define S_CONST 2.1972245773362196f

static __device__ __forceinline__ float sigm(float v) {
    return 1.0f / (1.0f + __expf(-v));
}

static __device__ __forceinline__ void pair_from_idx(int p, int& I, int& J) {
    int i = 0;
    while (p >= NTILE - i) { p -= NTILE - i; i++; }
    I = i; J = i + p;
}

// m[i,j] = ba_i*bu_j + ba_j*bu_i + bc_i*bg_j + bc_j*bg_i + bu_i*bg_j + bu_j*bg_i
static __device__ __forceinline__ float compute_m(const float* xI, const float* xJ, int r, int c) {
    float bai = xI[0*TILE + r], bui = xI[1*TILE + r], bci = xI[2*TILE + r], bgi = xI[3*TILE + r];
    float baj = xJ[0*TILE + c], buj = xJ[1*TILE + c], bcj = xJ[2*TILE + c], bgj = xJ[3*TILE + c];
    return bai*buj + baj*bui + bci*bgj + bcj*bgi + bui*bgj + buj*bgi;
}

// h = relu(W1 f + b1); out = relu(W2 h + b2).  w: [0..8]=W1 row-major [o][i], [9..11]=b1, [12..14]=W2, [15]=b2
static __device__ __forceinline__ float mlp3(float f0, float f1, float f2, const float* w) {
    float h0 = fmaxf(w[0]*f0 + w[1]*f1 + w[2]*f2 + w[9],  0.0f);
    float h1 = fmaxf(w[3]*f0 + w[4]*f1 + w[5]*f2 + w[10], 0.0f);
    float h2 = fmaxf(w[6]*f0 + w[7]*f1 + w[8]*f2 + w[11], 0.0f);
    return fmaxf(w[12]*h0 + w[13]*h1 + w[14]*h2 + w[15], 0.0f);
}

static __device__ __forceinline__ float ahnew_calc(float ah, float grad, float uuv, const float* w) {
    float va = mlp3(ah, grad, uuv, w);       // a-MLP  (w[0..15])
    float vr = mlp3(ah, grad, uuv, w + 16);  // rho-MLP (w[16..31])
    float v = fmaxf(fabsf(va) - vr, 0.0f);   // relu(|a| - rho); >=0 so clip(-1,1) == min(.,1)
    return fminf(v, 1.0f);
}

// uu = soft_sign(u - S)*u ; a_hat0 = sigmoid(uu)*soft_sign(uu - S)
__global__ void k_prep(const float* __restrict__ u,
                       float* __restrict__ uu, float* __restrict__ ahat) {
    const long long N = (long long)BB * LL * LL;
    for (long long i = (long long)blockIdx.x * blockDim.x + threadIdx.x; i < N;
         i += (long long)gridDim.x * blockDim.x) {
        float uv  = u[i];
        float uuv = sigm(2.0f * (uv - S_CONST)) * uv;
        float ah  = sigm(uuv) * sigm(2.0f * (uuv - S_CONST));
        uu[i]   = uuv;
        ahat[i] = ah;
    }
}

// rowsums of a0 = 0.5*(ah_ij^2 + ah_ji^2)*m  (tile-pair; a0 not materialized)
__global__ __launch_bounds__(256) void k_rs0(const float* __restrict__ ahat,
                                             const float* __restrict__ x,
                                             float* __restrict__ rs) {
    __shared__ float stB[TILE * SPAD];
    __shared__ float xI[4 * TILE], xJ[4 * TILE];
    __shared__ float rsI[TILE], rsJ[TILE];

    int b = blockIdx.x / NPAIR, p = blockIdx.x % NPAIR;
    int I, J; pair_from_idx(p, I, J);
    int Ib = I * TILE, Jb = J * TILE;
    bool diag = (I == J);
    int tid = threadIdx.x, c = tid & 63, rg = tid >> 6;

    { int row = tid >> 2, k = tid & 3;
      xI[k*TILE + row] = x[((size_t)b*LL + Ib + row)*4 + k];
      xJ[k*TILE + row] = x[((size_t)b*LL + Jb + row)*4 + k]; }
    if (tid < TILE) { rsI[tid] = 0.0f; rsJ[tid] = 0.0f; }

    // prefetch IJ tile into registers (all loads in flight before use)
    float ahv[16];
    size_t baseIJ = ((size_t)b*LL + Ib)*LL + Jb;
    #pragma unroll
    for (int k = 0; k < 16; k++)
        ahv[k] = ahat[baseIJ + (size_t)(rg + 4*k)*LL + c];

    size_t baseJI = ((size_t)b*LL + Jb)*LL + Ib;
    #pragma unroll
    for (int k = 0; k < 16; k++) {
        int xr = rg + 4*k;
        stB[xr*SPAD + c] = ahat[baseJI + (size_t)xr*LL + c];
    }
    __syncthreads();

    float rsJ_th = 0.0f;
    #pragma unroll
    for (int k = 0; k < 16; k++) {
        int r = rg + 4*k;
        float ah_ij = ahv[k];
        float ah_ji = stB[c*SPAD + r];
        float m = compute_m(xI, xJ, r, c);
        float a_val = 0.5f * (ah_ij*ah_ij + ah_ji*ah_ji) * m;
        float s = a_val;
        for (int off = 32; off; off >>= 1) s += __shfl_down(s, off, 64);
        if (c == 0) rsI[r] += s;
        if (!diag) rsJ_th += a_val;
    }
    if (!diag) atomicAdd(&rsJ[c], rsJ_th);
    __syncthreads();
    if (tid < TILE) atomicAdd(&rs[b*LL + Ib + tid], rsI[tid]);
    else if (!diag && tid < 2*TILE) atomicAdd(&rs[b*LL + Jb + (tid - TILE)], rsJ[tid - TILE]);
}

__global__ void k_rows_init(const float* __restrict__ rs0, float* __restrict__ lmbd,
                            float* __restrict__ ls, float* __restrict__ rs_other) {
    int i = blockIdx.x * blockDim.x + threadIdx.x;
    if (i < BB*LL) {
        float rsv = rs0[i];
        float l = fmaxf(rsv - 1.0f, 0.0f);   // W_PEN = 1
        lmbd[i] = l;
        ls[i] = l * sigm(2.0f * (rsv - 1.0f));
        rs_other[i] = 0.0f;
    }
}

__global__ __launch_bounds__(256) void k_step(
        const float* __restrict__ uu, float* __restrict__ ahat,
        const float* __restrict__ x,
        const float* __restrict__ ls, float* __restrict__ rs_next,
        const float* __restrict__ aW1, const float* __restrict__ ab1,
        const float* __restrict__ aW2, const float* __restrict__ ab2,
        const float* __restrict__ rW1, const float* __restrict__ rb1,
        const float* __restrict__ rW2, const float* __restrict__ rb2,
        float* __restrict__ out, int t) {
    __shared__ float stA[TILE * SPAD];   // uu_JI, then reused as a_val staging for JI tile
    __shared__ float stB[TILE * SPAD];   // ahat_JI, then reused as ah_new staging for JI tile
    __shared__ float xI[4 * TILE], xJ[4 * TILE];
    __shared__ float lsI[TILE], lsJ[TILE];
    __shared__ float w[32];
    __shared__ float rsI[TILE], rsJ[TILE];

    int b = blockIdx.x / NPAIR, p = blockIdx.x % NPAIR;
    int I, J; pair_from_idx(p, I, J);
    int Ib = I * TILE, Jb = J * TILE;
    bool diag = (I == J);
    int tid = threadIdx.x, c = tid & 63, rg = tid >> 6;

    // ---- phase 1: issue ALL IJ-tile loads into registers (no alias hazard,
    // 32 outstanding vmem ops per thread hide HBM latency) ----
    float uuv[16], ahv[16];
    size_t baseIJ = ((size_t)b*LL + Ib)*LL + Jb;
    #pragma unroll
    for (int k = 0; k < 16; k++) {
        size_t idx = baseIJ + (size_t)(rg + 4*k)*LL + c;
        uuv[k] = uu[idx];
        ahv[k] = ahat[idx];
    }

    // ---- phase 2: small loads + JI tile -> LDS ----
    if (tid < 32) {
        float v;
        if      (tid <  9) v = aW1[t*9 + tid];
        else if (tid < 12) v = ab1[t*3 + (tid-9)];
        else if (tid < 15) v = aW2[t*3 + (tid-12)];
        else if (tid < 16) v = ab2[t];
        else if (tid < 25) v = rW1[t*9 + (tid-16)];
        else if (tid < 28) v = rb1[t*3 + (tid-25)];
        else if (tid < 31) v = rW2[t*3 + (tid-28)];
        else               v = rb2[t];
        w[tid] = v;
    }
    { int row = tid >> 2, k = tid & 3;
      xI[k*TILE + row] = x[((size_t)b*LL + Ib + row)*4 + k];
      xJ[k*TILE + row] = x[((size_t)b*LL + Jb + row)*4 + k]; }
    if (tid < TILE) {
        lsI[tid] = ls[b*LL + Ib + tid];
        lsJ[tid] = ls[b*LL + Jb + tid];
        rsI[tid] = 0.0f; rsJ[tid] = 0.0f;
    }
    size_t baseJI = ((size_t)b*LL + Jb)*LL + Ib;
    #pragma unroll
    for (int k = 0; k < 16; k++) {
        int xr = rg + 4*k;
        stA[xr*SPAD + c] = uu[baseJI + (size_t)xr*LL + c];
        stB[xr*SPAD + c] = ahat[baseJI + (size_t)xr*LL + c];
    }
    __syncthreads();

    // ---- phase 3: compute from registers/LDS; stores only, no loads after stores ----
    size_t outBase = (((size_t)t*BB + b) * LL) * LL;
    float rsJ_th = 0.0f;
    #pragma unroll
    for (int k = 0; k < 16; k++) {
        int r = rg + 4*k;
        size_t idxIJ = baseIJ + (size_t)r*LL + c;
        float uu_ij = uuv[k];
        float ah_ij = ahv[k];
        float uu_ji = stA[c*SPAD + r];   // read before slot reuse (same thread owns slot)
        float ah_ji = stB[c*SPAD + r];
        float m = compute_m(xI, xJ, r, c);
        float gsum = -0.5f * (uu_ij + uu_ji) + lsI[r] + lsJ[c];
        float an_ij = ahnew_calc(ah_ij, ah_ij * m * gsum, uu_ij, w);
        float an_ji = ahnew_calc(ah_ji, ah_ji * m * gsum, uu_ji, w);  // diag: duplicate but correct
        float a_val = 0.5f * (an_ij*an_ij + an_ji*an_ji) * m;

        ahat[idxIJ] = an_ij;                                         // in-place: tile owned by block
        out[outBase + (size_t)(Ib + r)*LL + (Jb + c)] = a_val;

        float s = a_val;
        for (int off = 32; off; off >>= 1) s += __shfl_down(s, off, 64);
        if (c == 0) rsI[r] += s;                                     // wave-unique r, no race

        if (!diag) {
            stA[c*SPAD + r] = a_val;   // stage JI-tile output for coalesced writeback
            stB[c*SPAD + r] = an_ji;
            rsJ_th += a_val;           // a[Jb+c][Ib+r] == a_val (a symmetric)
        }
    }
    if (!diag) atomicAdd(&rsJ[c], rsJ_th);
    __syncthreads();
    if (!diag) {
        #pragma unroll
        for (int k = 0; k < 16; k++) {
            int xr = rg + 4*k;
            ahat[baseJI + (size_t)xr*LL + c] = stB[xr*SPAD + c];
            out[outBase + (size_t)(Jb + xr)*LL + (Ib + c)] = stA[xr*SPAD + c];
        }
    }
    if (tid < TILE) atomicAdd(&rs_next[b*LL + Ib + tid], rsI[tid]);
    else if (!diag && tid < 2*TILE) atomicAdd(&rs_next[b*LL + Jb + (tid - TILE)], rsJ[tid - TILE]);
}

__global__ void k_rows_step(const float* __restrict__ rs_new, float* lmbd, float* __restrict__ ls,
                            float* __restrict__ rs_zero,
                            const float* __restrict__ lW1, const float* __restrict__ lb1,
                            const float* __restrict__ lW2, const float* __restrict__ lb2,
                            int t) {
    int i = blockIdx.x * blockDim.x + threadIdx.x;
    if (i < BB*LL) {
        float rsv = rs_new[i];
        float lg = fmaxf(rsv - 1.0f, 0.0f);
        float l0 = lmbd[i];
        float w0 = lW1[t*6 + 0], w1 = lW1[t*6 + 1];
        float w2 = lW1[t*6 + 2], w3 = lW1[t*6 + 3];
        float w4 = lW1[t*6 + 4], w5 = lW1[t*6 + 5];
        float b0 = lb1[t*3 + 0], b1 = lb1[t*3 + 1];
        float b2 = lb1[t*3 + 2];
        float v0 = lW2[t*3 + 0], v1 = lW2[t*3 + 1];
        float v2 = lW2[t*3 + 2];
        float c2 = lb2[t];
        float h0 = fmaxf(w0*l0 + w1*lg + b0, 0.0f);
        float h1 = fmaxf(w2*l0 + w3*lg + b1, 0.0f);
        float h2 = fmaxf(w4*l0 + w5*lg + b2, 0.0f);
        float ln = fmaxf(v0*h0 + v1*h1 + v2*h2 + c2, 0.0f);
        lmbd[i] = ln;
        ls[i] = ln * sigm(2.0f * (rsv - 1.0f));
        rs_zero[i] = 0.0f;   // prepare next accumulator
    }
}

extern "C" void kernel_launch(void* const* d_in, const int* in_sizes, int n_in,
                              void* d_out, int out_size, void* d_ws, size_t ws_size,
                              hipStream_t stream) {
    const float* u   = (const float*)d_in[0];
    const float* x   = (const float*)d_in[1];
    const float* aW1 = (const float*)d_in[3];
    const float* ab1 = (const float*)d_in[4];
    const float* aW2 = (const float*)d_in[5];
    const float* ab2 = (const float*)d_in[6];
    const float* rW1 = (const float*)d_in[7];
    const float* rb1 = (const float*)d_in[8];
    const float* rW2 = (const float*)d_in[9];
    const float* rb2 = (const float*)d_in[10];
    const float* lW1 = (const float*)d_in[11];
    const float* lb1 = (const float*)d_in[12];
    const float* lW2 = (const float*)d_in[13];
    const float* lb2 = (const float*)d_in[14];
    float* out = (float*)d_out;

    char* ws = (char*)d_ws;
    size_t matBytes = (size_t)BB * LL * LL * sizeof(float);
    float* uu   = (float*)ws;
    float* ahat = (float*)(ws + matBytes);
    float* rs0  = (float*)(ws + 2 * matBytes);
    float* rs1  = rs0 + BB*LL;
    float* lmbd = rs1 + BB*LL;
    float* ls   = lmbd + BB*LL;

    hipMemsetAsync(rs0, 0, BB*LL*sizeof(float), stream);
    hipLaunchKernelGGL(k_prep, dim3(2048), dim3(256), 0, stream, u, uu, ahat);
    hipLaunchKernelGGL(k_rs0, dim3(BB*NPAIR), dim3(256), 0, stream, ahat, x, rs0);
    hipLaunchKernelGGL(k_rows_init, dim3((BB*LL)/256), dim3(256), 0, stream, rs0, lmbd, ls, rs1);

    float* rsb[2] = {rs0, rs1};
    for (int t = 0; t < TT; ++t) {
        hipLaunchKernelGGL(k_step, dim3(BB*NPAIR), dim3(256), 0, stream,
                           uu, ahat, x, ls, rsb[(t+1)&1],
                           aW1, ab1, aW2, ab2, rW1, rb1, rW2, rb2, out, t);
        hipLaunchKernelGGL(k_rows_step, dim3((BB*LL)/256), dim3(256), 0, stream,
                           rsb[(t+1)&1], lmbd, ls, rsb[t&1], lW1, lb1, lW2, lb2, t);
    }
}

// Round 6
// 665.291 us; speedup vs baseline: 1.1139x; 1.0653x over previous
//
#include <hip/hip_runtime.h>
#include <hip/hip_bf16.h>

#define BB 8
#define LL 1024
#define TT 10
#define TILE 64
#define NTILE (LL/TILE)            // 16
#define NPAIR (NTILE*(NTILE+1)/2)  // 136
#define SPAD 65                    // 64 + 1 pad, conflict-free transpose reads
#define S_CONST 2.1972245773362196f

typedef __hip_bfloat16 bf16;

static __device__ __forceinline__ float sigm(float v) {
    return 1.0f / (1.0f + __expf(-v));
}

static __device__ __forceinline__ void pair_from_idx(int p, int& I, int& J) {
    int i = 0;
    while (p >= NTILE - i) { p -= NTILE - i; i++; }
    I = i; J = i + p;
}

// m[i,j] = ba_i*bu_j + ba_j*bu_i + bc_i*bg_j + bc_j*bg_i + bu_i*bg_j + bu_j*bg_i
static __device__ __forceinline__ float compute_m(const float* xI, const float* xJ, int r, int c) {
    float bai = xI[0*TILE + r], bui = xI[1*TILE + r], bci = xI[2*TILE + r], bgi = xI[3*TILE + r];
    float baj = xJ[0*TILE + c], buj = xJ[1*TILE + c], bcj = xJ[2*TILE + c], bgj = xJ[3*TILE + c];
    return bai*buj + baj*bui + bci*bgj + bcj*bgi + bui*bgj + buj*bgi;
}

// h = relu(W1 f + b1); out = relu(W2 h + b2).  w: [0..8]=W1 row-major [o][i], [9..11]=b1, [12..14]=W2, [15]=b2
static __device__ __forceinline__ float mlp3(float f0, float f1, float f2, const float* w) {
    float h0 = fmaxf(w[0]*f0 + w[1]*f1 + w[2]*f2 + w[9],  0.0f);
    float h1 = fmaxf(w[3]*f0 + w[4]*f1 + w[5]*f2 + w[10], 0.0f);
    float h2 = fmaxf(w[6]*f0 + w[7]*f1 + w[8]*f2 + w[11], 0.0f);
    return fmaxf(w[12]*h0 + w[13]*h1 + w[14]*h2 + w[15], 0.0f);
}

static __device__ __forceinline__ float ahnew_calc(float ah, float grad, float uuv, const float* w) {
    float va = mlp3(ah, grad, uuv, w);       // a-MLP  (w[0..15])
    float vr = mlp3(ah, grad, uuv, w + 16);  // rho-MLP (w[16..31])
    float v = fmaxf(fabsf(va) - vr, 0.0f);   // relu(|a| - rho); >=0 so clip(-1,1) == min(.,1)
    return fminf(v, 1.0f);
}

// uu = soft_sign(u - S)*u ; a_hat0 = sigmoid(uu)*soft_sign(uu - S)   (bf16 state)
__global__ void k_prep(const float* __restrict__ u,
                       bf16* __restrict__ uu, bf16* __restrict__ ahat) {
    const long long N = (long long)BB * LL * LL;
    for (long long i = (long long)blockIdx.x * blockDim.x + threadIdx.x; i < N;
         i += (long long)gridDim.x * blockDim.x) {
        float uv  = u[i];
        float uuv = sigm(2.0f * (uv - S_CONST)) * uv;
        float ah  = sigm(uuv) * sigm(2.0f * (uuv - S_CONST));
        uu[i]   = __float2bfloat16(uuv);
        ahat[i] = __float2bfloat16(ah);
    }
}

// rowsums of a0 = 0.5*(ah_ij^2 + ah_ji^2)*m  (tile-pair; a0 not materialized)
__global__ __launch_bounds__(256) void k_rs0(const bf16* __restrict__ ahat,
                                             const float* __restrict__ x,
                                             float* __restrict__ rs) {
    __shared__ float stB[TILE * SPAD];
    __shared__ float xI[4 * TILE], xJ[4 * TILE];
    __shared__ float rsI[TILE], rsJ[TILE];

    int b = blockIdx.x / NPAIR, p = blockIdx.x % NPAIR;
    int I, J; pair_from_idx(p, I, J);
    int Ib = I * TILE, Jb = J * TILE;
    bool diag = (I == J);
    int tid = threadIdx.x, c = tid & 63, rg = tid >> 6;

    { int row = tid >> 2, k = tid & 3;
      xI[k*TILE + row] = x[((size_t)b*LL + Ib + row)*4 + k];
      xJ[k*TILE + row] = x[((size_t)b*LL + Jb + row)*4 + k]; }
    if (tid < TILE) { rsI[tid] = 0.0f; rsJ[tid] = 0.0f; }

    float ahv[16];
    size_t baseIJ = ((size_t)b*LL + Ib)*LL + Jb;
    #pragma unroll
    for (int k = 0; k < 16; k++)
        ahv[k] = __bfloat162float(ahat[baseIJ + (size_t)(rg + 4*k)*LL + c]);

    size_t baseJI = ((size_t)b*LL + Jb)*LL + Ib;
    #pragma unroll
    for (int k = 0; k < 16; k++) {
        int xr = rg + 4*k;
        stB[xr*SPAD + c] = __bfloat162float(ahat[baseJI + (size_t)xr*LL + c]);
    }
    __syncthreads();

    float rsJ_th = 0.0f;
    #pragma unroll
    for (int k = 0; k < 16; k++) {
        int r = rg + 4*k;
        float ah_ij = ahv[k];
        float ah_ji = stB[c*SPAD + r];
        float m = compute_m(xI, xJ, r, c);
        float a_val = 0.5f * (ah_ij*ah_ij + ah_ji*ah_ji) * m;
        float s = a_val;
        for (int off = 32; off; off >>= 1) s += __shfl_down(s, off, 64);
        if (c == 0) rsI[r] += s;
        if (!diag) rsJ_th += a_val;
    }
    if (!diag) atomicAdd(&rsJ[c], rsJ_th);
    __syncthreads();
    if (tid < TILE) atomicAdd(&rs[b*LL + Ib + tid], rsI[tid]);
    else if (!diag && tid < 2*TILE) atomicAdd(&rs[b*LL + Jb + (tid - TILE)], rsJ[tid - TILE]);
}

__global__ void k_rows_init(const float* __restrict__ rs0, float* __restrict__ lmbd,
                            float* __restrict__ ls, float* __restrict__ rs_other) {
    int i = blockIdx.x * blockDim.x + threadIdx.x;
    if (i < BB*LL) {
        float rsv = rs0[i];
        float l = fmaxf(rsv - 1.0f, 0.0f);   // W_PEN = 1
        lmbd[i] = l;
        ls[i] = l * sigm(2.0f * (rsv - 1.0f));
        rs_other[i] = 0.0f;
    }
}

__global__ __launch_bounds__(256) void k_step(
        const bf16* __restrict__ uu, bf16* __restrict__ ahat,
        const float* __restrict__ x,
        const float* __restrict__ ls, float* __restrict__ rs_next,
        const float* __restrict__ aW1, const float* __restrict__ ab1,
        const float* __restrict__ aW2, const float* __restrict__ ab2,
        const float* __restrict__ rW1, const float* __restrict__ rb1,
        const float* __restrict__ rW2, const float* __restrict__ rb2,
        float* __restrict__ out, int t) {
    __shared__ float stA[TILE * SPAD];   // uu_JI, then reused as a_val staging for JI tile
    __shared__ float stB[TILE * SPAD];   // ahat_JI, then reused as ah_new staging for JI tile
    __shared__ float xI[4 * TILE], xJ[4 * TILE];
    __shared__ float lsI[TILE], lsJ[TILE];
    __shared__ float w[32];
    __shared__ float rsI[TILE], rsJ[TILE];

    int b = blockIdx.x / NPAIR, p = blockIdx.x % NPAIR;
    int I, J; pair_from_idx(p, I, J);
    int Ib = I * TILE, Jb = J * TILE;
    bool diag = (I == J);
    int tid = threadIdx.x, c = tid & 63, rg = tid >> 6;

    // ---- phase 1: issue ALL IJ-tile loads into registers ----
    float uuv[16], ahv[16];
    size_t baseIJ = ((size_t)b*LL + Ib)*LL + Jb;
    #pragma unroll
    for (int k = 0; k < 16; k++) {
        size_t idx = baseIJ + (size_t)(rg + 4*k)*LL + c;
        uuv[k] = __bfloat162float(uu[idx]);
        ahv[k] = __bfloat162float(ahat[idx]);
    }

    // ---- phase 2: small loads + JI tile -> LDS ----
    if (tid < 32) {
        float v;
        if      (tid <  9) v = aW1[t*9 + tid];
        else if (tid < 12) v = ab1[t*3 + (tid-9)];
        else if (tid < 15) v = aW2[t*3 + (tid-12)];
        else if (tid < 16) v = ab2[t];
        else if (tid < 25) v = rW1[t*9 + (tid-16)];
        else if (tid < 28) v = rb1[t*3 + (tid-25)];
        else if (tid < 31) v = rW2[t*3 + (tid-28)];
        else               v = rb2[t];
        w[tid] = v;
    }
    { int row = tid >> 2, k = tid & 3;
      xI[k*TILE + row] = x[((size_t)b*LL + Ib + row)*4 + k];
      xJ[k*TILE + row] = x[((size_t)b*LL + Jb + row)*4 + k]; }
    if (tid < TILE) {
        lsI[tid] = ls[b*LL + Ib + tid];
        lsJ[tid] = ls[b*LL + Jb + tid];
        rsI[tid] = 0.0f; rsJ[tid] = 0.0f;
    }
    size_t baseJI = ((size_t)b*LL + Jb)*LL + Ib;
    #pragma unroll
    for (int k = 0; k < 16; k++) {
        int xr = rg + 4*k;
        stA[xr*SPAD + c] = __bfloat162float(uu[baseJI + (size_t)xr*LL + c]);
        stB[xr*SPAD + c] = __bfloat162float(ahat[baseJI + (size_t)xr*LL + c]);
    }
    __syncthreads();

    // ---- phase 3: compute from registers/LDS; stores only ----
    size_t outBase = (((size_t)t*BB + b) * LL) * LL;
    float rsJ_th = 0.0f;
    #pragma unroll
    for (int k = 0; k < 16; k++) {
        int r = rg + 4*k;
        size_t idxIJ = baseIJ + (size_t)r*LL + c;
        float uu_ij = uuv[k];
        float ah_ij = ahv[k];
        float uu_ji = stA[c*SPAD + r];   // read before slot reuse (same thread owns slot)
        float ah_ji = stB[c*SPAD + r];
        float m = compute_m(xI, xJ, r, c);
        float gsum = -0.5f * (uu_ij + uu_ji) + lsI[r] + lsJ[c];
        float an_ij = ahnew_calc(ah_ij, ah_ij * m * gsum, uu_ij, w);
        float an_ji = ahnew_calc(ah_ji, ah_ji * m * gsum, uu_ji, w);  // diag: duplicate but correct
        float a_val = 0.5f * (an_ij*an_ij + an_ji*an_ji) * m;

        ahat[idxIJ] = __float2bfloat16(an_ij);                       // in-place: tile owned by block
        __builtin_nontemporal_store(a_val, &out[outBase + (size_t)(Ib + r)*LL + (Jb + c)]);

        float s = a_val;
        for (int off = 32; off; off >>= 1) s += __shfl_down(s, off, 64);
        if (c == 0) rsI[r] += s;                                     // wave-unique r, no race

        if (!diag) {
            stA[c*SPAD + r] = a_val;   // stage JI-tile output for coalesced writeback
            stB[c*SPAD + r] = an_ji;
            rsJ_th += a_val;           // a[Jb+c][Ib+r] == a_val (a symmetric)
        }
    }
    if (!diag) atomicAdd(&rsJ[c], rsJ_th);
    __syncthreads();
    if (!diag) {
        #pragma unroll
        for (int k = 0; k < 16; k++) {
            int xr = rg + 4*k;
            ahat[baseJI + (size_t)xr*LL + c] = __float2bfloat16(stB[xr*SPAD + c]);
            __builtin_nontemporal_store(stA[xr*SPAD + c],
                                        &out[outBase + (size_t)(Jb + xr)*LL + (Ib + c)]);
        }
    }
    if (tid < TILE) atomicAdd(&rs_next[b*LL + Ib + tid], rsI[tid]);
    else if (!diag && tid < 2*TILE) atomicAdd(&rs_next[b*LL + Jb + (tid - TILE)], rsJ[tid - TILE]);
}

__global__ void k_rows_step(const float* __restrict__ rs_new, float* lmbd, float* __restrict__ ls,
                            float* __restrict__ rs_zero,
                            const float* __restrict__ lW1, const float* __restrict__ lb1,
                            const float* __restrict__ lW2, const float* __restrict__ lb2,
                            int t) {
    int i = blockIdx.x * blockDim.x + threadIdx.x;
    if (i < BB*LL) {
        float rsv = rs_new[i];
        float lg = fmaxf(rsv - 1.0f, 0.0f);
        float l0 = lmbd[i];
        float w0 = lW1[t*6 + 0], w1 = lW1[t*6 + 1];
        float w2 = lW1[t*6 + 2], w3 = lW1[t*6 + 3];
        float w4 = lW1[t*6 + 4], w5 = lW1[t*6 + 5];
        float b0 = lb1[t*3 + 0], b1 = lb1[t*3 + 1];
        float b2 = lb1[t*3 + 2];
        float v0 = lW2[t*3 + 0], v1 = lW2[t*3 + 1];
        float v2 = lW2[t*3 + 2];
        float c2 = lb2[t];
        float h0 = fmaxf(w0*l0 + w1*lg + b0, 0.0f);
        float h1 = fmaxf(w2*l0 + w3*lg + b1, 0.0f);
        float h2 = fmaxf(w4*l0 + w5*lg + b2, 0.0f);
        float ln = fmaxf(v0*h0 + v1*h1 + v2*h2 + c2, 0.0f);
        lmbd[i] = ln;
        ls[i] = ln * sigm(2.0f * (rsv - 1.0f));
        rs_zero[i] = 0.0f;   // prepare next accumulator
    }
}

extern "C" void kernel_launch(void* const* d_in, const int* in_sizes, int n_in,
                              void* d_out, int out_size, void* d_ws, size_t ws_size,
                              hipStream_t stream) {
    const float* u   = (const float*)d_in[0];
    const float* x   = (const float*)d_in[1];
    const float* aW1 = (const float*)d_in[3];
    const float* ab1 = (const float*)d_in[4];
    const float* aW2 = (const float*)d_in[5];
    const float* ab2 = (const float*)d_in[6];
    const float* rW1 = (const float*)d_in[7];
    const float* rb1 = (const float*)d_in[8];
    const float* rW2 = (const float*)d_in[9];
    const float* rb2 = (const float*)d_in[10];
    const float* lW1 = (const float*)d_in[11];
    const float* lb1 = (const float*)d_in[12];
    const float* lW2 = (const float*)d_in[13];
    const float* lb2 = (const float*)d_in[14];
    float* out = (float*)d_out;

    char* ws = (char*)d_ws;
    size_t matB2 = (size_t)BB * LL * LL * sizeof(bf16);
    bf16* uu   = (bf16*)ws;
    bf16* ahat = (bf16*)(ws + matB2);
    float* rs0  = (float*)(ws + 2 * matB2);
    float* rs1  = rs0 + BB*LL;
    float* lmbd = rs1 + BB*LL;
    float* ls   = lmbd + BB*LL;

    hipMemsetAsync(rs0, 0, BB*LL*sizeof(float), stream);
    hipLaunchKernelGGL(k_prep, dim3(2048), dim3(256), 0, stream, u, uu, ahat);
    hipLaunchKernelGGL(k_rs0, dim3(BB*NPAIR), dim3(256), 0, stream, ahat, x, rs0);
    hipLaunchKernelGGL(k_rows_init, dim3((BB*LL)/256), dim3(256), 0, stream, rs0, lmbd, ls, rs1);

    float* rsb[2] = {rs0, rs1};
    for (int t = 0; t < TT; ++t) {
        hipLaunchKernelGGL(k_step, dim3(BB*NPAIR), dim3(256), 0, stream,
                           uu, ahat, x, ls, rsb[(t+1)&1],
                           aW1, ab1, aW2, ab2, rW1, rb1, rW2, rb2, out, t);
        hipLaunchKernelGGL(k_rows_step, dim3((BB*LL)/256), dim3(256), 0, stream,
                           rsb[(t+1)&1], lmbd, ls, rsb[t&1], lW1, lb1, lW2, lb2, t);
    }
}